// Round 10
// baseline (3663.505 us; speedup 1.0000x reference)
//
#include <hip/hip_runtime.h>

// PDM (delta-sigma) encode, bit-exact vs fp32 reference:
//   x = w*0.5f + 0.5f; u = e + x; s = u>0; e' = s ? u-1 : u; out = s ? 1 : 0
// Latency-bound serial scan: 128 rows x 160000 steps, 2 waves on the chip.
//
// R10: LDS-staged pipeline. Register-buffer asm staging failed 5x on RA /
// lazy-VGPR-read hazards (R4-R9). New structure has no in-flight op whose
// source/dest registers the compiler can recycle:
//   input : global_load_lds DMA -> LDS (no dest regs), triple-buffered,
//           one vmcnt(0) drain per phase (order-free; ~770cy cover)
//   LDS->reg: 16x volatile asm ds_read_b128 + lgkmcnt(0) drain (single-type
//           counter; asm defs pin the batch against sinking)
//   output: plain C stores -- compiler owns them and inserts correct waits
// Compute sequence identical to R1 (verified absmax 0.0).

#define T_LEN 160000
#define CHUNK 64
#define NPC 16              // 16B pieces per chunk per lane
#define NC (T_LEN / CHUNK)  // 2500 chunks
#define BUFB (NPC * 64 * 16)  // bytes per LDS buffer (16 KiB)

typedef float f32x4 __attribute__((ext_vector_type(4)));
#define AS1 __attribute__((address_space(1)))
#define AS3 __attribute__((address_space(3)))

#define SB() __builtin_amdgcn_sched_barrier(0)
#define DRAIN_VM() do { asm volatile("s_waitcnt vmcnt(0)" ::: "memory"); SB(); } while (0)
#define DRAIN_LGKM() do { asm volatile("s_waitcnt lgkmcnt(0)" ::: "memory"); SB(); } while (0)

// volatile ds_read pins issue position; "=v" def pins the value in regs
#define DSREAD(dst, addr, OFF) \
    asm volatile("ds_read_b128 %0, %1 offset:" #OFF : "=v"(dst) : "v"(addr))

// ---- bit-exact compute (identical op sequence to the fp32 reference) ----
__device__ __forceinline__ void pdm_step(float v, float& e, float& o) {
    float x = v * 0.5f + 0.5f;  // exact mul -> same rounding as (v/2)+0.5
    float u = e + x;            // chain level 1
    bool sp = u > 0.0f;         // level 2 (cmp) || (u-1) sub
    o = sp ? 1.0f : 0.0f;       // off-chain cndmask
    e = sp ? (u - 1.0f) : u;    // level 3 cndmask
}

__device__ __forceinline__ f32x4 pdm_piece(f32x4 v, float& e) {
    float r0, r1, r2, r3;
    pdm_step(v[0], e, r0);
    pdm_step(v[1], e, r1);
    pdm_step(v[2], e, r2);
    pdm_step(v[3], e, r3);
    f32x4 r; r[0] = r0; r[1] = r1; r[2] = r2; r[3] = r3;
    return r;
}

__global__ __launch_bounds__(64, 1)
void pdm_encode(const float* __restrict__ w, float* __restrict__ out, int nRows) {
    // lds[buf][piece][lane][4]: DMA j writes lane*16 at &lds[b][j][0][0]
    __shared__ float lds[3][NPC][64][4];   // 48 KiB

    const int lane = threadIdx.x;
    const int row = blockIdx.x * 64 + lane;
    if (row >= nRows) return;              // never taken at B=128

    const float* src = w + (size_t)row * T_LEN;
    float* dst = out + (size_t)row * T_LEN;

    const unsigned lds0 = (unsigned)(uintptr_t)(AS3 float*)&lds[0][0][0][0];
    const unsigned myoff = lds0 + (unsigned)lane * 16u;   // this lane's slot

    // DMA chunk c into buffer b: 16 pieces of 16B/lane. Wave-uniform LDS
    // dest (+lane*16 implicit), per-lane global src. No dest registers.
    #define DMA(b_, c_) do {                                               \
        const float* _g = src + (size_t)(c_) * CHUNK;                      \
        _Pragma("unroll")                                                  \
        for (int j = 0; j < NPC; ++j)                                      \
            __builtin_amdgcn_global_load_lds(                              \
                (const AS1 void*)(_g + j * 4),                             \
                (AS3 void*)&lds[b_][j][0][0], 16, 0, 0);                   \
    } while (0)

    DMA(0, 0); DMA(1, 1); DMA(2, 2);       // 48 in flight (<= 63)

    float e = 0.0f;

    for (int c = 0; c < NC; ++c) {
        const int b = c % 3;               // uniform SALU
        const unsigned boff = myoff + (unsigned)b * BUFB;

        DRAIN_VM();                        // chunk c's DMA (and older) done

        // batched LDS -> regs: 16 pinned ds_read_b128, then full lgkm drain
        f32x4 v0,v1,v2,v3,v4,v5,v6,v7,v8,v9,v10,v11,v12,v13,v14,v15;
        DSREAD(v0,  boff, 0);     DSREAD(v1,  boff, 1024);
        DSREAD(v2,  boff, 2048);  DSREAD(v3,  boff, 3072);
        DSREAD(v4,  boff, 4096);  DSREAD(v5,  boff, 5120);
        DSREAD(v6,  boff, 6144);  DSREAD(v7,  boff, 7168);
        DSREAD(v8,  boff, 8192);  DSREAD(v9,  boff, 9216);
        DSREAD(v10, boff, 10240); DSREAD(v11, boff, 11264);
        DSREAD(v12, boff, 12288); DSREAD(v13, boff, 13312);
        DSREAD(v14, boff, 14336); DSREAD(v15, boff, 15360);
        DRAIN_LGKM();                      // all 16 returned before compute

        if (c < NC - 3) DMA(b, c + 3);     // refill freed buffer; flies
                                           // under this phase's compute

        // compute chunk c in timestep order; stores are compiler-owned
        float* dc = dst + (size_t)c * CHUNK;
        *(f32x4*)(dc +  0) = pdm_piece(v0,  e);
        *(f32x4*)(dc +  4) = pdm_piece(v1,  e);
        *(f32x4*)(dc +  8) = pdm_piece(v2,  e);
        *(f32x4*)(dc + 12) = pdm_piece(v3,  e);
        *(f32x4*)(dc + 16) = pdm_piece(v4,  e);
        *(f32x4*)(dc + 20) = pdm_piece(v5,  e);
        *(f32x4*)(dc + 24) = pdm_piece(v6,  e);
        *(f32x4*)(dc + 28) = pdm_piece(v7,  e);
        *(f32x4*)(dc + 32) = pdm_piece(v8,  e);
        *(f32x4*)(dc + 36) = pdm_piece(v9,  e);
        *(f32x4*)(dc + 40) = pdm_piece(v10, e);
        *(f32x4*)(dc + 44) = pdm_piece(v11, e);
        *(f32x4*)(dc + 48) = pdm_piece(v12, e);
        *(f32x4*)(dc + 52) = pdm_piece(v13, e);
        *(f32x4*)(dc + 56) = pdm_piece(v14, e);
        *(f32x4*)(dc + 60) = pdm_piece(v15, e);
    }
    #undef DMA
}

extern "C" void kernel_launch(void* const* d_in, const int* in_sizes, int n_in,
                              void* d_out, int out_size, void* d_ws, size_t ws_size,
                              hipStream_t stream) {
    const float* w = (const float*)d_in[0];
    float* out = (float*)d_out;

    const int nRows = in_sizes[0] / T_LEN;   // B = 128
    const int block = 64;
    const int grid = (nRows + block - 1) / block;  // 2 blocks, 1 wave each

    pdm_encode<<<grid, block, 0, stream>>>(w, out, nRows);
}